// Round 4
// baseline (511.724 us; speedup 1.0000x reference)
//
#include <hip/hip_runtime.h>
#include <stdint.h>

#define TT 2048      // T
#define CC 2048      // C
#define NHEAD 16
#define HD 128
#define NB 4         // batch
#define MTOT (NB*TT) // 8192
#define KD 2048      // GEMM K (both projections)
#define NT 32        // K tiles of 64

typedef __attribute__((ext_vector_type(8))) short bf16x8;
typedef __attribute__((ext_vector_type(4))) float f32x4;

__device__ __forceinline__ unsigned short f2bf(float f) {
  unsigned u = __float_as_uint(f);
  u += 0x7FFF + ((u >> 16) & 1);
  return (unsigned short)(u >> 16);
}
__device__ __forceinline__ float bf2f(unsigned short h) {
  return __uint_as_float(((unsigned)h) << 16);
}

__device__ __forceinline__ void gl_lds16(const unsigned short* g, short* l) {
  __builtin_amdgcn_global_load_lds(
      (const __attribute__((address_space(1))) void*)(g),
      (__attribute__((address_space(3))) void*)(l), 16, 0, 0);
}

#define MFMA16(a, b, c) __builtin_amdgcn_mfma_f32_16x16x32_bf16((a), (b), (c), 0, 0, 0)

// m201-style phase discipline: NO sched_barrier pinning inside the phase
// (m141: full pinning = 1.7x loss). One sched_barrier after the post-barrier
// blocks next-phase STAGE from hoisting above it (the only real hazard).
#define PRE_MFMA() do { \
  __builtin_amdgcn_s_barrier(); \
  asm volatile("s_waitcnt lgkmcnt(0)" ::: "memory"); \
  __builtin_amdgcn_s_setprio(1); \
} while(0)
#define POST_MFMA() do { \
  __builtin_amdgcn_s_setprio(0); \
  __builtin_amdgcn_s_barrier(); \
  __builtin_amdgcn_sched_barrier(0); \
} while(0)

// ---------------- fp32 -> bf16 cast ----------------
__global__ void k_f2b(const float* __restrict__ in, unsigned short* __restrict__ out, int n4) {
  int i = blockIdx.x * 256 + threadIdx.x;
  if (i >= n4) return;
  float4 v = reinterpret_cast<const float4*>(in)[i];
  ushort4 o;
  o.x = f2bf(v.x); o.y = f2bf(v.y); o.z = f2bf(v.z); o.w = f2bf(v.w);
  reinterpret_cast<ushort4*>(out)[i] = o;
}

// ---------------- RoPE table (fp64 on device; matches np ref closely) ----------------
__global__ void k_rope_tab(float* __restrict__ tab) {
  int t = blockIdx.x, i = threadIdx.x;  // 2048 x 64
  double inv = exp2(-(double)i * (13.287712379549449062 / 64.0)); // 10000^(-i/64)
  double ang = (double)t * inv;
  tab[(t*64 + i)*2 + 0] = (float)cos(ang);
  tab[(t*64 + i)*2 + 1] = (float)sin(ang);
}

// ================= 256x256 8-wave phase-scheduled GEMM core =================
// C[m][n] = sum_k A[m][k]*B[n][k]; A:[M][2048], B:[N][2048] row-major bf16 bits.
// 512 thr = 8 waves (2M x 4N); per-wave 128x64 out; acc[8][4].
// LDS 128KB: A panels [2 dbuf][256][64] at 0; B panels at 32768 (shorts).
// Chunk-XOR swizzle: 16B chunk c of row r stored at slot c^(r&7); staged via
// pre-swizzled global source (linear LDS dest) -- rule 21 involution.
// Schedule per tile t (4 phases, quadrant GM=q&1, GN=q>>1):
//   q0: read A(GM0)+B(ni0,1), stage A-half0(t+1);  q1: read A(GM1)+B(ni2,3), stage A-half1(t+1)
//   q2: read A(GM0), stage B-half0(t+2);           q3: read A(GM1), stage B-half1(t+2), vmcnt(4)
// B freed after q1 (reg-cached) -> B(t+2) into own buffer at q2/q3 is safe.
// Steady-state vmcnt(4) at q3 completes B(t+1)+A(t+1) (issued >=3 phases prior),
// leaves B(t+2)'s 4 loads in flight -- counted, never drain-0 until the tail.
__device__ __forceinline__ void gemm256_core(
    const unsigned short* __restrict__ Ag,
    const unsigned short* __restrict__ Bg,
    int m0, int n0, short* lds, f32x4 (&acc)[8][4])
{
  const int tid = threadIdx.x;
  const int wid = tid >> 6, lane = tid & 63;
  const int wm = wid >> 2, wn = wid & 3;
  const int r15 = lane & 15, hi4 = lane >> 4;
  const int srow = wid*8 + (lane >> 3);
  const int schunk = (lane & 7) ^ (lane >> 3);

  const f32x4 fz = {0.f, 0.f, 0.f, 0.f};
#pragma unroll
  for (int i = 0; i < 8; i++)
#pragma unroll
    for (int j = 0; j < 4; j++) acc[i][j] = fz;

  int aoff0[8];
#pragma unroll
  for (int mi = 0; mi < 8; mi++) {
    int row = wm*128 + mi*16 + r15;
    aoff0[mi] = row*64 + ((hi4 ^ (row & 7))*8);
  }
  int boff0[4];
#pragma unroll
  for (int ni = 0; ni < 4; ni++) {
    int row = wn*64 + ni*16 + r15;
    boff0[ni] = row*64 + ((hi4 ^ (row & 7))*8);
  }

#define STAGE(G, L, GROW0, KT) do { \
    gl_lds16((G) + (size_t)((GROW0) + srow)*KD + (KT) + schunk*8, (L) + wid*512); \
    gl_lds16((G) + (size_t)((GROW0) + 64 + srow)*KD + (KT) + schunk*8, (L) + 4096 + wid*512); \
  } while(0)

  // prologue: B(0), A(0) [must complete], then B(1) [may stay in flight]
  STAGE(Bg, lds + 32768,                n0,       0);
  STAGE(Bg, lds + 32768 + 8192,         n0 + 128, 0);
  STAGE(Ag, lds,                        m0,       0);
  STAGE(Ag, lds + 8192,                 m0 + 128, 0);
  STAGE(Bg, lds + 32768 + 16384,        n0,       64);
  STAGE(Bg, lds + 32768 + 16384 + 8192, n0 + 128, 64);
  asm volatile("s_waitcnt vmcnt(4)" ::: "memory");
  __builtin_amdgcn_s_barrier();
  __builtin_amdgcn_sched_barrier(0);

  bf16x8 breg[4][2];

#pragma unroll 1
  for (int t = 0; t < NT; t++) {
    const int db = t & 1;
    short* Ab = lds + db*16384;
    short* Bb = lds + 32768 + db*16384;
    short* An = lds + (db ^ 1)*16384;
    const int kt = t*64;
    const bool stA = (t < NT - 1);
    const bool stB = (t < NT - 2);

    // ---- phase 0: GM=0, GN=0 ----
    {
      bf16x8 a[4][2];
#pragma unroll
      for (int mi = 0; mi < 4; mi++) {
        a[mi][0] = *reinterpret_cast<const bf16x8*>(Ab + aoff0[mi]);
        a[mi][1] = *reinterpret_cast<const bf16x8*>(Ab + (aoff0[mi] ^ 32));
      }
#pragma unroll
      for (int ni = 0; ni < 2; ni++) {
        breg[ni][0] = *reinterpret_cast<const bf16x8*>(Bb + boff0[ni]);
        breg[ni][1] = *reinterpret_cast<const bf16x8*>(Bb + (boff0[ni] ^ 32));
      }
      if (stA) STAGE(Ag, An, m0, kt + 64);
      PRE_MFMA();
#pragma unroll
      for (int mi = 0; mi < 4; mi++)
#pragma unroll
        for (int ni = 0; ni < 2; ni++) {
          acc[mi][ni] = MFMA16(a[mi][0], breg[ni][0], acc[mi][ni]);
          acc[mi][ni] = MFMA16(a[mi][1], breg[ni][1], acc[mi][ni]);
        }
      POST_MFMA();
    }
    // ---- phase 1: GM=1, GN=0 ----
    {
      bf16x8 a[4][2];
#pragma unroll
      for (int mi = 0; mi < 4; mi++) {
        a[mi][0] = *reinterpret_cast<const bf16x8*>(Ab + aoff0[4 + mi]);
        a[mi][1] = *reinterpret_cast<const bf16x8*>(Ab + (aoff0[4 + mi] ^ 32));
      }
#pragma unroll
      for (int ni = 2; ni < 4; ni++) {
        breg[ni][0] = *reinterpret_cast<const bf16x8*>(Bb + boff0[ni]);
        breg[ni][1] = *reinterpret_cast<const bf16x8*>(Bb + (boff0[ni] ^ 32));
      }
      if (stA) STAGE(Ag, An + 8192, m0 + 128, kt + 64);
      PRE_MFMA();
#pragma unroll
      for (int mi = 0; mi < 4; mi++)
#pragma unroll
        for (int ni = 0; ni < 2; ni++) {
          acc[4 + mi][ni] = MFMA16(a[mi][0], breg[ni][0], acc[4 + mi][ni]);
          acc[4 + mi][ni] = MFMA16(a[mi][1], breg[ni][1], acc[4 + mi][ni]);
        }
      POST_MFMA();
    }
    // ---- phase 2: GM=0, GN=1 ----
    {
      bf16x8 a[4][2];
#pragma unroll
      for (int mi = 0; mi < 4; mi++) {
        a[mi][0] = *reinterpret_cast<const bf16x8*>(Ab + aoff0[mi]);
        a[mi][1] = *reinterpret_cast<const bf16x8*>(Ab + (aoff0[mi] ^ 32));
      }
      if (stB) STAGE(Bg, Bb, n0, kt + 128);
      PRE_MFMA();
#pragma unroll
      for (int mi = 0; mi < 4; mi++)
#pragma unroll
        for (int ni = 0; ni < 2; ni++) {
          acc[mi][2 + ni] = MFMA16(a[mi][0], breg[2 + ni][0], acc[mi][2 + ni]);
          acc[mi][2 + ni] = MFMA16(a[mi][1], breg[2 + ni][1], acc[mi][2 + ni]);
        }
      POST_MFMA();
    }
    // ---- phase 3: GM=1, GN=1 ----
    {
      bf16x8 a[4][2];
#pragma unroll
      for (int mi = 0; mi < 4; mi++) {
        a[mi][0] = *reinterpret_cast<const bf16x8*>(Ab + aoff0[4 + mi]);
        a[mi][1] = *reinterpret_cast<const bf16x8*>(Ab + (aoff0[4 + mi] ^ 32));
      }
      if (stB) STAGE(Bg, Bb + 8192, n0 + 128, kt + 128);
      if (t >= NT - 2) asm volatile("s_waitcnt vmcnt(0)" ::: "memory");
      else             asm volatile("s_waitcnt vmcnt(4)" ::: "memory");
      PRE_MFMA();
#pragma unroll
      for (int mi = 0; mi < 4; mi++)
#pragma unroll
        for (int ni = 0; ni < 2; ni++) {
          acc[4 + mi][2 + ni] = MFMA16(a[mi][0], breg[2 + ni][0], acc[4 + mi][2 + ni]);
          acc[4 + mi][2 + ni] = MFMA16(a[mi][1], breg[2 + ni][1], acc[4 + mi][2 + ni]);
        }
      POST_MFMA();
    }
  }
#undef STAGE
}

// ---------------- QKV projection + scatter (q,k -> [B,H,T,D]; v -> [B,H,D,T]) ----------------
__global__ __launch_bounds__(512, 2) void k_qkv(
    const unsigned short* __restrict__ xb,
    const unsigned short* __restrict__ wab,
    unsigned short* __restrict__ qr,
    unsigned short* __restrict__ kr,
    unsigned short* __restrict__ vt)
{
  __shared__ __align__(16) short lds[65536];
  f32x4 acc[8][4];
  int bid = blockIdx.x;                      // 768 blocks = 32 mt x 24 nt
  int swz = (bid & 7)*96 + (bid >> 3);       // bijective XCD swizzle (768 % 8 == 0)
  int m0 = (swz / 24)*256, n0 = (swz % 24)*256;
  gemm256_core(xb, wab, m0, n0, lds, acc);

  int tid = threadIdx.x, wid = tid >> 6, lane = tid & 63;
  int wm = wid >> 2, wn = wid & 3, r15 = lane & 15, hi4 = lane >> 4;
  int nw0 = n0 + wn*64;
  int which = nw0 >> 11;            // 0=q, 1=k, 2=v
  int h = (nw0 & 2047) >> 7;        // head (wave's 64 cols lie in one head)
#pragma unroll
  for (int mi = 0; mi < 8; mi++) {
    int m_base = m0 + wm*128 + mi*16 + hi4*4;
    int b = m_base >> 11;
    int t0 = m_base & (TT - 1);
#pragma unroll
    for (int ni = 0; ni < 4; ni++) {
      int d = (nw0 & 127) + ni*16 + r15;
      if (which == 2) {
        ushort4 pv;
        pv.x = f2bf(acc[mi][ni][0]); pv.y = f2bf(acc[mi][ni][1]);
        pv.z = f2bf(acc[mi][ni][2]); pv.w = f2bf(acc[mi][ni][3]);
        *reinterpret_cast<ushort4*>(vt + ((size_t)((b*NHEAD + h)*HD + d))*TT + t0) = pv;
      } else {
        unsigned short* dst = (which == 0) ? qr : kr;
        size_t base = ((size_t)(b*NHEAD + h)*TT + t0)*HD + d;
#pragma unroll
        for (int r = 0; r < 4; r++) dst[base + (size_t)r*HD] = f2bf(acc[mi][ni][r]);
      }
    }
  }
}

// ---------------- output projection ----------------
__global__ __launch_bounds__(512, 2) void k_proj(
    const unsigned short* __restrict__ yb,
    const unsigned short* __restrict__ wpb,
    float* __restrict__ out)
{
  __shared__ __align__(16) short lds[65536];
  f32x4 acc[8][4];
  int bid = blockIdx.x;                      // 256 blocks = 32 mt x 8 nt
  int swz = (bid & 7)*32 + (bid >> 3);
  int m0 = (swz / 8)*256, n0 = (swz % 8)*256;
  gemm256_core(yb, wpb, m0, n0, lds, acc);

  int tid = threadIdx.x, wid = tid >> 6, lane = tid & 63;
  int wm = wid >> 2, wn = wid & 3, r15 = lane & 15, hi4 = lane >> 4;
  int nw0 = n0 + wn*64;
#pragma unroll
  for (int mi = 0; mi < 8; mi++) {
    int m = m0 + wm*128 + mi*16 + hi4*4;
#pragma unroll
    for (int ni = 0; ni < 4; ni++) {
      int n = nw0 + ni*16 + r15;
#pragma unroll
      for (int r = 0; r < 4; r++)
        out[(size_t)(m + r)*CC + n] = acc[mi][ni][r];
    }
  }
}

// ---------------- in-place RoPE on q,k ----------------
__global__ void k_rope_apply(unsigned int* __restrict__ q32, unsigned int* __restrict__ k32,
                             const float* __restrict__ tab) {
  int i = blockIdx.x * 256 + threadIdx.x;   // over B*H*T*64
  int ii = i & 63;
  int t = (i >> 6) & (TT - 1);
  float c = tab[(t*64 + ii)*2], s = tab[(t*64 + ii)*2 + 1];
  unsigned qv = q32[i];
  float q1 = bf2f((unsigned short)qv), q2 = bf2f((unsigned short)(qv >> 16));
  unsigned short lo = f2bf(q1*c - q2*s), hi = f2bf(q1*s + q2*c);
  q32[i] = (unsigned)lo | ((unsigned)hi << 16);
  unsigned kv = k32[i];
  float k1 = bf2f((unsigned short)kv), k2 = bf2f((unsigned short)(kv >> 16));
  lo = f2bf(k1*c - k2*s); hi = f2bf(k1*s + k2*c);
  k32[i] = (unsigned)lo | ((unsigned)hi << 16);
}

// ---------------- causal flash attention, load-balanced ----------------
// grid: 1024 blocks = 64 (b*h) * 16 q-tile PAIRS (pr, 31-pr) -> uniform 33 KV tiles/block
__global__ __launch_bounds__(256) void k_attn(
    const unsigned short* __restrict__ qr,
    const unsigned short* __restrict__ kr,
    const unsigned short* __restrict__ vt,
    unsigned short* __restrict__ yb)
{
  __shared__ short Ks[64*128];   // [kv][d], XOR-swizzled
  __shared__ short Vs[128*64];   // [d][kv], XOR-swizzled
  __shared__ short Pw[4*16*64];  // per-wave P, XOR-swizzled
  int bid = blockIdx.x;
  int bh = bid & 63, pr = bid >> 6;
  int tid = threadIdx.x, w = tid >> 6, lane = tid & 63;
  int r15 = lane & 15, hi4 = lane >> 4;
  const unsigned short* qg = qr + (size_t)bh*TT*HD;
  const unsigned short* kg = kr + (size_t)bh*TT*HD;
  const unsigned short* vg = vt + (size_t)bh*HD*TT;
  const f32x4 fz = {0.f,0.f,0.f,0.f};
  const float scale = 0.08838834764831845f; // 1/sqrt(128)
  int b = bh >> 4, h = bh & 15;

#pragma unroll 1
  for (int ph = 0; ph < 2; ph++) {
    int qb = ph ? (31 - pr) : pr;
    int qlo = qb*64 + w*16;
    bf16x8 qf[4];
    {
      int qrow = qlo + r15;
#pragma unroll
      for (int kk = 0; kk < 4; kk++)
        qf[kk] = *reinterpret_cast<const bf16x8*>(qg + (size_t)qrow*HD + kk*32 + hi4*8);
    }
    f32x4 ao[8];
#pragma unroll
    for (int i = 0; i < 8; i++) ao[i] = fz;
    float mrow[4], lsum[4];
#pragma unroll
    for (int r = 0; r < 4; r++) { mrow[r] = -3.0e38f; lsum[r] = 0.f; }
    int ntiles = qb + 1;
    for (int it = 0; it < ntiles; ++it) {
      int kv0 = it*64;
      __syncthreads();
#pragma unroll
      for (int i = 0; i < 4; i++) {
        int chunk = tid + i*256;
        int row = chunk >> 4, c16 = chunk & 15;
        uint4 v = *reinterpret_cast<const uint4*>(kg + (size_t)(kv0 + row)*HD + c16*8);
        *reinterpret_cast<uint4*>((char*)Ks + row*256 + ((c16 ^ (row & 7))*16)) = v;
      }
#pragma unroll
      for (int i = 0; i < 4; i++) {
        int chunk = tid + i*256;
        int d = chunk >> 3, c8 = chunk & 7;
        uint4 v = *reinterpret_cast<const uint4*>(vg + (size_t)d*TT + kv0 + c8*8);
        *reinterpret_cast<uint4*>((char*)Vs + d*128 + ((c8 ^ (d & 7))*16)) = v;
      }
      __syncthreads();
      f32x4 sacc[4];
#pragma unroll
      for (int n = 0; n < 4; n++) {
        sacc[n] = fz;
#pragma unroll
        for (int kk = 0; kk < 4; kk++) {
          int kvr = n*16 + r15;
          int ch = (kk*4 + hi4) ^ (kvr & 7);
          bf16x8 kf = *reinterpret_cast<const bf16x8*>((char*)Ks + kvr*256 + ch*16);
          sacc[n] = MFMA16(qf[kk], kf, sacc[n]);
        }
      }
      float p[4][4], rmax[4];
#pragma unroll
      for (int r = 0; r < 4; r++) {
        int qgi = qlo + hi4*4 + r;
        float mx = -3.0e38f;
#pragma unroll
        for (int n = 0; n < 4; n++) {
          int kvg = kv0 + n*16 + r15;
          float sv = sacc[n][r]*scale;
          sv = (kvg <= qgi) ? sv : -3.0e38f;
          p[n][r] = sv;
          mx = fmaxf(mx, sv);
        }
        rmax[r] = mx;
      }
#pragma unroll
      for (int mm = 1; mm < 16; mm <<= 1)
#pragma unroll
        for (int r = 0; r < 4; r++) rmax[r] = fmaxf(rmax[r], __shfl_xor(rmax[r], mm));
      float alpha[4], rsum[4];
#pragma unroll
      for (int r = 0; r < 4; r++) {
        float mnew = fmaxf(mrow[r], rmax[r]);
        alpha[r] = __expf(mrow[r] - mnew);
        mrow[r] = mnew;
        float sum = 0.f;
#pragma unroll
        for (int n = 0; n < 4; n++) {
          float pv = __expf(p[n][r] - mnew);
          p[n][r] = pv;
          sum += pv;
        }
        rsum[r] = sum;
      }
#pragma unroll
      for (int mm = 1; mm < 16; mm <<= 1)
#pragma unroll
        for (int r = 0; r < 4; r++) rsum[r] += __shfl_xor(rsum[r], mm);
#pragma unroll
      for (int r = 0; r < 4; r++) lsum[r] = lsum[r]*alpha[r] + rsum[r];
#pragma unroll
      for (int i = 0; i < 8; i++)
#pragma unroll
        for (int r = 0; r < 4; r++) ao[i][r] *= alpha[r];
#pragma unroll
      for (int r = 0; r < 4; r++) {
        int prow = hi4*4 + r;
#pragma unroll
        for (int n = 0; n < 4; n++) {
          int col = n*16 + r15;
          Pw[w*1024 + prow*64 + (col ^ ((prow & 7) << 3))] = (short)f2bf(p[n][r]);
        }
      }
#pragma unroll
      for (int kk = 0; kk < 2; kk++) {
        int prow = r15;
        int ch = (kk*4 + hi4) ^ (prow & 7);
        bf16x8 pa = *reinterpret_cast<const bf16x8*>((char*)(Pw + w*1024) + prow*128 + ch*16);
#pragma unroll
        for (int ds_ = 0; ds_ < 8; ds_++) {
          int d = ds_*16 + r15;
          int vch = (kk*4 + hi4) ^ (d & 7);
          bf16x8 vf = *reinterpret_cast<const bf16x8*>((char*)Vs + d*128 + vch*16);
          ao[ds_] = MFMA16(pa, vf, ao[ds_]);
        }
      }
    }
#pragma unroll
    for (int r = 0; r < 4; r++) {
      int t = qlo + hi4*4 + r;
      float inv = 1.f / lsum[r];
      size_t base = ((size_t)b*TT + t)*CC + h*HD + r15;
#pragma unroll
      for (int ds_ = 0; ds_ < 8; ds_++)
        yb[base + ds_*16] = f2bf(ao[ds_][r] * inv);
    }
  }
}

extern "C" void kernel_launch(void* const* d_in, const int* in_sizes, int n_in,
                              void* d_out, int out_size, void* d_ws, size_t ws_size,
                              hipStream_t stream) {
  const float* x  = (const float*)d_in[0];
  const float* wa = (const float*)d_in[1];
  const float* wp = (const float*)d_in[2];
  float* out = (float*)d_out;
  char* ws = (char*)d_ws;
  size_t off = 0;
  unsigned short* xb  = (unsigned short*)(ws + off); off += (size_t)MTOT*CC*2;
  unsigned short* wab = (unsigned short*)(ws + off); off += (size_t)3*CC*CC*2;
  unsigned short* wpb = (unsigned short*)(ws + off); off += (size_t)CC*CC*2;
  unsigned short* qr  = (unsigned short*)(ws + off); off += (size_t)MTOT*CC*2;
  unsigned short* kr  = (unsigned short*)(ws + off); off += (size_t)MTOT*CC*2;
  unsigned short* vt  = (unsigned short*)(ws + off); off += (size_t)MTOT*CC*2;
  unsigned short* yb  = (unsigned short*)(ws + off); off += (size_t)MTOT*CC*2;
  float* tab          = (float*)(ws + off);          off += (size_t)TT*64*2*4;

  k_f2b<<<dim3(16384), dim3(256), 0, stream>>>(x,  xb,  MTOT*CC/4);
  k_f2b<<<dim3(12288), dim3(256), 0, stream>>>(wa, wab, 3*CC*CC/4);
  k_f2b<<<dim3(4096),  dim3(256), 0, stream>>>(wp, wpb, CC*CC/4);
  k_rope_tab<<<dim3(TT), dim3(64), 0, stream>>>(tab);
  k_qkv<<<dim3(768), dim3(512), 0, stream>>>(xb, wab, qr, kr, vt);
  k_rope_apply<<<dim3(32768), dim3(256), 0, stream>>>((unsigned int*)qr, (unsigned int*)kr, tab);
  k_attn<<<dim3(1024), dim3(256), 0, stream>>>(qr, kr, vt, yb);
  k_proj<<<dim3(256), dim3(512), 0, stream>>>(yb, wpb, out);
}

// Round 5
// 494.615 us; speedup vs baseline: 1.0346x; 1.0346x over previous
//
#include <hip/hip_runtime.h>
#include <stdint.h>

#define TT 2048      // T
#define CC 2048      // C
#define NHEAD 16
#define HD 128
#define NB 4         // batch
#define MTOT (NB*TT) // 8192
#define KD 2048      // GEMM K (both projections)
#define NT 32        // K tiles of 64

typedef __attribute__((ext_vector_type(8))) short bf16x8;
typedef __attribute__((ext_vector_type(4))) float f32x4;

__device__ __forceinline__ unsigned short f2bf(float f) {
  unsigned u = __float_as_uint(f);
  u += 0x7FFF + ((u >> 16) & 1);
  return (unsigned short)(u >> 16);
}
__device__ __forceinline__ float bf2f(unsigned short h) {
  return __uint_as_float(((unsigned)h) << 16);
}

__device__ __forceinline__ void gl_lds16(const unsigned short* g, short* l) {
  __builtin_amdgcn_global_load_lds(
      (const __attribute__((address_space(1))) void*)(g),
      (__attribute__((address_space(3))) void*)(l), 16, 0, 0);
}

#define MFMA16(a, b, c) __builtin_amdgcn_mfma_f32_16x16x32_bf16((a), (b), (c), 0, 0, 0)

#define PRE_MFMA() do { \
  __builtin_amdgcn_s_barrier(); \
  asm volatile("s_waitcnt lgkmcnt(0)" ::: "memory"); \
  __builtin_amdgcn_s_setprio(1); \
} while(0)
#define POST_MFMA() do { \
  __builtin_amdgcn_s_setprio(0); \
  __builtin_amdgcn_s_barrier(); \
  __builtin_amdgcn_sched_barrier(0); \
} while(0)

// ---------------- fp32 -> bf16 cast ----------------
__global__ void k_f2b(const float* __restrict__ in, unsigned short* __restrict__ out, int n4) {
  int i = blockIdx.x * 256 + threadIdx.x;
  if (i >= n4) return;
  float4 v = reinterpret_cast<const float4*>(in)[i];
  ushort4 o;
  o.x = f2bf(v.x); o.y = f2bf(v.y); o.z = f2bf(v.z); o.w = f2bf(v.w);
  reinterpret_cast<ushort4*>(out)[i] = o;
}

// ---------------- RoPE table (fp64 on device; matches np ref closely) ----------------
__global__ void k_rope_tab(float* __restrict__ tab) {
  int t = blockIdx.x, i = threadIdx.x;  // 2048 x 64
  double inv = exp2(-(double)i * (13.287712379549449062 / 64.0)); // 10000^(-i/64)
  double ang = (double)t * inv;
  tab[(t*64 + i)*2 + 0] = (float)cos(ang);
  tab[(t*64 + i)*2 + 1] = (float)sin(ang);
}

// ================= 256x256 8-wave kk-split GEMM core =================
// C[m][n] = sum_k A[m][k]*B[n][k]; A:[M][2048], B:[N][2048] row-major bf16 bits.
// 512 thr = 8 waves (2M x 4N); per-wave 128x64 out; acc[8][4].
// LDS 128KB: A panels [2 dbuf][256][64] at 0; B panels at 32768 (shorts).
// Chunk-XOR swizzle (rule 21 involution): 16B chunk c of row r at slot c^(r&7).
// Per K-tile: 2 phases (kk=0,1), read-once fragments (24 ds_read_b128/wave,
// was 40 with quadrant phases), 4 barriers (was 8):
//   ph0: read A[mi0-7][kk0] (8) + B[all][kk0,kk1] (8); stage A(t+1) both halves
//        (opposite buffer -> always safe); bar; lgkm0; 32 MFMA (kk0); bar.
//   ph1: read A[mi0-7][kk1] (8); stage B(t+2) into live B buffer -- SAFE because
//        every wave's B(t) reads completed at ph0's lgkm0+barrier; vmcnt(4)
//        (FIFO completes B(t+1)+A(t+1), leaves B(t+2) flying); bar; lgkm0;
//        32 MFMA (kk1); bar.
// Accumulation order per acc element unchanged (kk0 then kk1).
__device__ __forceinline__ void gemm256_core(
    const unsigned short* __restrict__ Ag,
    const unsigned short* __restrict__ Bg,
    int m0, int n0, short* lds, f32x4 (&acc)[8][4])
{
  const int tid = threadIdx.x;
  const int wid = tid >> 6, lane = tid & 63;
  const int wm = wid >> 2, wn = wid & 3;
  const int r15 = lane & 15, hi4 = lane >> 4;
  const int srow = wid*8 + (lane >> 3);
  const int schunk = (lane & 7) ^ (lane >> 3);

  const f32x4 fz = {0.f, 0.f, 0.f, 0.f};
#pragma unroll
  for (int i = 0; i < 8; i++)
#pragma unroll
    for (int j = 0; j < 4; j++) acc[i][j] = fz;

  int aoff0[8];
#pragma unroll
  for (int mi = 0; mi < 8; mi++) {
    int row = wm*128 + mi*16 + r15;
    aoff0[mi] = row*64 + ((hi4 ^ (row & 7))*8);
  }
  int boff0[4];
#pragma unroll
  for (int ni = 0; ni < 4; ni++) {
    int row = wn*64 + ni*16 + r15;
    boff0[ni] = row*64 + ((hi4 ^ (row & 7))*8);
  }

#define STAGE(G, L, GROW0, KT) do { \
    gl_lds16((G) + (size_t)((GROW0) + srow)*KD + (KT) + schunk*8, (L) + wid*512); \
    gl_lds16((G) + (size_t)((GROW0) + 64 + srow)*KD + (KT) + schunk*8, (L) + 4096 + wid*512); \
  } while(0)

  // prologue: A(0), B(0) [must complete], then B(1) [may stay in flight]
  STAGE(Ag, lds,                        m0,       0);
  STAGE(Ag, lds + 8192,                 m0 + 128, 0);
  STAGE(Bg, lds + 32768,                n0,       0);
  STAGE(Bg, lds + 32768 + 8192,         n0 + 128, 0);
  STAGE(Bg, lds + 32768 + 16384,        n0,       64);
  STAGE(Bg, lds + 32768 + 16384 + 8192, n0 + 128, 64);
  asm volatile("s_waitcnt vmcnt(4)" ::: "memory");
  __builtin_amdgcn_s_barrier();
  __builtin_amdgcn_sched_barrier(0);

#pragma unroll 1
  for (int t = 0; t < NT; t++) {
    const int db = t & 1;
    short* Ab = lds + db*16384;
    short* Bb = lds + 32768 + db*16384;
    short* An = lds + (db ^ 1)*16384;
    const int kt = t*64;
    const bool stA = (t < NT - 1);
    const bool stB = (t < NT - 2);

    bf16x8 a[8], b[4][2];
    // ---- phase 0: kk=0 ----
#pragma unroll
    for (int mi = 0; mi < 8; mi++)
      a[mi] = *reinterpret_cast<const bf16x8*>(Ab + aoff0[mi]);
#pragma unroll
    for (int ni = 0; ni < 4; ni++) {
      b[ni][0] = *reinterpret_cast<const bf16x8*>(Bb + boff0[ni]);
      b[ni][1] = *reinterpret_cast<const bf16x8*>(Bb + (boff0[ni] ^ 32));
    }
    if (stA) {
      STAGE(Ag, An,        m0,       kt + 64);
      STAGE(Ag, An + 8192, m0 + 128, kt + 64);
    }
    PRE_MFMA();
#pragma unroll
    for (int mi = 0; mi < 8; mi++)
#pragma unroll
      for (int ni = 0; ni < 4; ni++)
        acc[mi][ni] = MFMA16(a[mi], b[ni][0], acc[mi][ni]);
    POST_MFMA();

    // ---- phase 1: kk=1 ----
#pragma unroll
    for (int mi = 0; mi < 8; mi++)
      a[mi] = *reinterpret_cast<const bf16x8*>(Ab + (aoff0[mi] ^ 32));
    if (stB) {
      STAGE(Bg, Bb,        n0,       kt + 128);
      STAGE(Bg, Bb + 8192, n0 + 128, kt + 128);
    }
    if (t >= NT - 2) asm volatile("s_waitcnt vmcnt(0)" ::: "memory");
    else             asm volatile("s_waitcnt vmcnt(4)" ::: "memory");
    PRE_MFMA();
#pragma unroll
    for (int mi = 0; mi < 8; mi++)
#pragma unroll
      for (int ni = 0; ni < 4; ni++)
        acc[mi][ni] = MFMA16(a[mi], b[ni][1], acc[mi][ni]);
    POST_MFMA();
  }
#undef STAGE
}

// ---------------- QKV projection + scatter (q,k -> [B,H,T,D]; v -> [B,H,D,T]) ----------------
__global__ __launch_bounds__(512, 2) void k_qkv(
    const unsigned short* __restrict__ xb,
    const unsigned short* __restrict__ wab,
    unsigned short* __restrict__ qr,
    unsigned short* __restrict__ kr,
    unsigned short* __restrict__ vt)
{
  __shared__ __align__(16) short lds[65536];
  f32x4 acc[8][4];
  int bid = blockIdx.x;                      // 768 blocks = 32 mt x 24 nt
  int swz = (bid & 7)*96 + (bid >> 3);       // bijective XCD swizzle (768 % 8 == 0)
  int m0 = (swz / 24)*256, n0 = (swz % 24)*256;
  gemm256_core(xb, wab, m0, n0, lds, acc);

  int tid = threadIdx.x, wid = tid >> 6, lane = tid & 63;
  int wm = wid >> 2, wn = wid & 3, r15 = lane & 15, hi4 = lane >> 4;
  int nw0 = n0 + wn*64;
  int which = nw0 >> 11;            // 0=q, 1=k, 2=v
  int h = (nw0 & 2047) >> 7;        // head (wave's 64 cols lie in one head)
#pragma unroll
  for (int mi = 0; mi < 8; mi++) {
    int m_base = m0 + wm*128 + mi*16 + hi4*4;
    int b = m_base >> 11;
    int t0 = m_base & (TT - 1);
#pragma unroll
    for (int ni = 0; ni < 4; ni++) {
      int d = (nw0 & 127) + ni*16 + r15;
      if (which == 2) {
        ushort4 pv;
        pv.x = f2bf(acc[mi][ni][0]); pv.y = f2bf(acc[mi][ni][1]);
        pv.z = f2bf(acc[mi][ni][2]); pv.w = f2bf(acc[mi][ni][3]);
        *reinterpret_cast<ushort4*>(vt + ((size_t)((b*NHEAD + h)*HD + d))*TT + t0) = pv;
      } else {
        unsigned short* dst = (which == 0) ? qr : kr;
        size_t base = ((size_t)(b*NHEAD + h)*TT + t0)*HD + d;
#pragma unroll
        for (int r = 0; r < 4; r++) dst[base + (size_t)r*HD] = f2bf(acc[mi][ni][r]);
      }
    }
  }
}

// ---------------- output projection ----------------
__global__ __launch_bounds__(512, 2) void k_proj(
    const unsigned short* __restrict__ yb,
    const unsigned short* __restrict__ wpb,
    float* __restrict__ out)
{
  __shared__ __align__(16) short lds[65536];
  f32x4 acc[8][4];
  int bid = blockIdx.x;                      // 256 blocks = 32 mt x 8 nt
  int swz = (bid & 7)*32 + (bid >> 3);
  int m0 = (swz / 8)*256, n0 = (swz % 8)*256;
  gemm256_core(yb, wpb, m0, n0, lds, acc);

  int tid = threadIdx.x, wid = tid >> 6, lane = tid & 63;
  int wm = wid >> 2, wn = wid & 3, r15 = lane & 15, hi4 = lane >> 4;
  int nw0 = n0 + wn*64;
#pragma unroll
  for (int mi = 0; mi < 8; mi++) {
    int m = m0 + wm*128 + mi*16 + hi4*4;
#pragma unroll
    for (int ni = 0; ni < 4; ni++) {
      int n = nw0 + ni*16 + r15;
#pragma unroll
      for (int r = 0; r < 4; r++)
        out[(size_t)(m + r)*CC + n] = acc[mi][ni][r];
    }
  }
}

// ---------------- in-place RoPE on q,k ----------------
__global__ void k_rope_apply(unsigned int* __restrict__ q32, unsigned int* __restrict__ k32,
                             const float* __restrict__ tab) {
  int i = blockIdx.x * 256 + threadIdx.x;   // over B*H*T*64
  int ii = i & 63;
  int t = (i >> 6) & (TT - 1);
  float c = tab[(t*64 + ii)*2], s = tab[(t*64 + ii)*2 + 1];
  unsigned qv = q32[i];
  float q1 = bf2f((unsigned short)qv), q2 = bf2f((unsigned short)(qv >> 16));
  unsigned short lo = f2bf(q1*c - q2*s), hi = f2bf(q1*s + q2*c);
  q32[i] = (unsigned)lo | ((unsigned)hi << 16);
  unsigned kv = k32[i];
  float k1 = bf2f((unsigned short)kv), k2 = bf2f((unsigned short)(kv >> 16));
  lo = f2bf(k1*c - k2*s); hi = f2bf(k1*s + k2*c);
  k32[i] = (unsigned)lo | ((unsigned)hi << 16);
}

// ---------------- causal flash attention, load-balanced ----------------
// grid: 1024 blocks = 64 (b*h) * 16 q-tile PAIRS (pr, 31-pr) -> uniform 33 KV tiles/block
__global__ __launch_bounds__(256) void k_attn(
    const unsigned short* __restrict__ qr,
    const unsigned short* __restrict__ kr,
    const unsigned short* __restrict__ vt,
    unsigned short* __restrict__ yb)
{
  __shared__ short Ks[64*128];   // [kv][d], XOR-swizzled
  __shared__ short Vs[128*64];   // [d][kv], XOR-swizzled
  __shared__ short Pw[4*16*64];  // per-wave P, XOR-swizzled
  int bid = blockIdx.x;
  int bh = bid & 63, pr = bid >> 6;
  int tid = threadIdx.x, w = tid >> 6, lane = tid & 63;
  int r15 = lane & 15, hi4 = lane >> 4;
  const unsigned short* qg = qr + (size_t)bh*TT*HD;
  const unsigned short* kg = kr + (size_t)bh*TT*HD;
  const unsigned short* vg = vt + (size_t)bh*HD*TT;
  const f32x4 fz = {0.f,0.f,0.f,0.f};
  const float scale = 0.08838834764831845f; // 1/sqrt(128)
  int b = bh >> 4, h = bh & 15;

#pragma unroll 1
  for (int ph = 0; ph < 2; ph++) {
    int qb = ph ? (31 - pr) : pr;
    int qlo = qb*64 + w*16;
    bf16x8 qf[4];
    {
      int qrow = qlo + r15;
#pragma unroll
      for (int kk = 0; kk < 4; kk++)
        qf[kk] = *reinterpret_cast<const bf16x8*>(qg + (size_t)qrow*HD + kk*32 + hi4*8);
    }
    f32x4 ao[8];
#pragma unroll
    for (int i = 0; i < 8; i++) ao[i] = fz;
    float mrow[4], lsum[4];
#pragma unroll
    for (int r = 0; r < 4; r++) { mrow[r] = -3.0e38f; lsum[r] = 0.f; }
    int ntiles = qb + 1;
    for (int it = 0; it < ntiles; ++it) {
      int kv0 = it*64;
      __syncthreads();
#pragma unroll
      for (int i = 0; i < 4; i++) {
        int chunk = tid + i*256;
        int row = chunk >> 4, c16 = chunk & 15;
        uint4 v = *reinterpret_cast<const uint4*>(kg + (size_t)(kv0 + row)*HD + c16*8);
        *reinterpret_cast<uint4*>((char*)Ks + row*256 + ((c16 ^ (row & 7))*16)) = v;
      }
#pragma unroll
      for (int i = 0; i < 4; i++) {
        int chunk = tid + i*256;
        int d = chunk >> 3, c8 = chunk & 7;
        uint4 v = *reinterpret_cast<const uint4*>(vg + (size_t)d*TT + kv0 + c8*8);
        *reinterpret_cast<uint4*>((char*)Vs + d*128 + ((c8 ^ (d & 7))*16)) = v;
      }
      __syncthreads();
      f32x4 sacc[4];
#pragma unroll
      for (int n = 0; n < 4; n++) {
        sacc[n] = fz;
#pragma unroll
        for (int kk = 0; kk < 4; kk++) {
          int kvr = n*16 + r15;
          int ch = (kk*4 + hi4) ^ (kvr & 7);
          bf16x8 kf = *reinterpret_cast<const bf16x8*>((char*)Ks + kvr*256 + ch*16);
          sacc[n] = MFMA16(qf[kk], kf, sacc[n]);
        }
      }
      float p[4][4], rmax[4];
#pragma unroll
      for (int r = 0; r < 4; r++) {
        int qgi = qlo + hi4*4 + r;
        float mx = -3.0e38f;
#pragma unroll
        for (int n = 0; n < 4; n++) {
          int kvg = kv0 + n*16 + r15;
          float sv = sacc[n][r]*scale;
          sv = (kvg <= qgi) ? sv : -3.0e38f;
          p[n][r] = sv;
          mx = fmaxf(mx, sv);
        }
        rmax[r] = mx;
      }
#pragma unroll
      for (int mm = 1; mm < 16; mm <<= 1)
#pragma unroll
        for (int r = 0; r < 4; r++) rmax[r] = fmaxf(rmax[r], __shfl_xor(rmax[r], mm));
      float alpha[4], rsum[4];
#pragma unroll
      for (int r = 0; r < 4; r++) {
        float mnew = fmaxf(mrow[r], rmax[r]);
        alpha[r] = __expf(mrow[r] - mnew);
        mrow[r] = mnew;
        float sum = 0.f;
#pragma unroll
        for (int n = 0; n < 4; n++) {
          float pv = __expf(p[n][r] - mnew);
          p[n][r] = pv;
          sum += pv;
        }
        rsum[r] = sum;
      }
#pragma unroll
      for (int mm = 1; mm < 16; mm <<= 1)
#pragma unroll
        for (int r = 0; r < 4; r++) rsum[r] += __shfl_xor(rsum[r], mm);
#pragma unroll
      for (int r = 0; r < 4; r++) lsum[r] = lsum[r]*alpha[r] + rsum[r];
#pragma unroll
      for (int i = 0; i < 8; i++)
#pragma unroll
        for (int r = 0; r < 4; r++) ao[i][r] *= alpha[r];
#pragma unroll
      for (int r = 0; r < 4; r++) {
        int prow = hi4*4 + r;
#pragma unroll
        for (int n = 0; n < 4; n++) {
          int col = n*16 + r15;
          Pw[w*1024 + prow*64 + (col ^ ((prow & 7) << 3))] = (short)f2bf(p[n][r]);
        }
      }
#pragma unroll
      for (int kk = 0; kk < 2; kk++) {
        int prow = r15;
        int ch = (kk*4 + hi4) ^ (prow & 7);
        bf16x8 pa = *reinterpret_cast<const bf16x8*>((char*)(Pw + w*1024) + prow*128 + ch*16);
#pragma unroll
        for (int ds_ = 0; ds_ < 8; ds_++) {
          int d = ds_*16 + r15;
          int vch = (kk*4 + hi4) ^ (d & 7);
          bf16x8 vf = *reinterpret_cast<const bf16x8*>((char*)Vs + d*128 + vch*16);
          ao[ds_] = MFMA16(pa, vf, ao[ds_]);
        }
      }
    }
#pragma unroll
    for (int r = 0; r < 4; r++) {
      int t = qlo + hi4*4 + r;
      float inv = 1.f / lsum[r];
      size_t base = ((size_t)b*TT + t)*CC + h*HD + r15;
#pragma unroll
      for (int ds_ = 0; ds_ < 8; ds_++)
        yb[base + ds_*16] = f2bf(ao[ds_][r] * inv);
    }
  }
}

extern "C" void kernel_launch(void* const* d_in, const int* in_sizes, int n_in,
                              void* d_out, int out_size, void* d_ws, size_t ws_size,
                              hipStream_t stream) {
  const float* x  = (const float*)d_in[0];
  const float* wa = (const float*)d_in[1];
  const float* wp = (const float*)d_in[2];
  float* out = (float*)d_out;
  char* ws = (char*)d_ws;
  size_t off = 0;
  unsigned short* xb  = (unsigned short*)(ws + off); off += (size_t)MTOT*CC*2;
  unsigned short* wab = (unsigned short*)(ws + off); off += (size_t)3*CC*CC*2;
  unsigned short* wpb = (unsigned short*)(ws + off); off += (size_t)CC*CC*2;
  unsigned short* qr  = (unsigned short*)(ws + off); off += (size_t)MTOT*CC*2;
  unsigned short* kr  = (unsigned short*)(ws + off); off += (size_t)MTOT*CC*2;
  unsigned short* vt  = (unsigned short*)(ws + off); off += (size_t)MTOT*CC*2;
  unsigned short* yb  = (unsigned short*)(ws + off); off += (size_t)MTOT*CC*2;
  float* tab          = (float*)(ws + off);          off += (size_t)TT*64*2*4;

  k_f2b<<<dim3(16384), dim3(256), 0, stream>>>(x,  xb,  MTOT*CC/4);
  k_f2b<<<dim3(12288), dim3(256), 0, stream>>>(wa, wab, 3*CC*CC/4);
  k_f2b<<<dim3(4096),  dim3(256), 0, stream>>>(wp, wpb, CC*CC/4);
  k_rope_tab<<<dim3(TT), dim3(64), 0, stream>>>(tab);
  k_qkv<<<dim3(768), dim3(512), 0, stream>>>(xb, wab, qr, kr, vt);
  k_rope_apply<<<dim3(32768), dim3(256), 0, stream>>>((unsigned int*)qr, (unsigned int*)kr, tab);
  k_attn<<<dim3(1024), dim3(256), 0, stream>>>(qr, kr, vt, yb);
  k_proj<<<dim3(256), dim3(512), 0, stream>>>(yb, wpb, out);
}